// Round 6
// baseline (530.506 us; speedup 1.0000x reference)
//
#include <hip/hip_runtime.h>
#include <hip/hip_fp16.h>

typedef _Float16 half2_t __attribute__((ext_vector_type(2)));
typedef _Float16 half4_t __attribute__((ext_vector_type(4)));
typedef _Float16 half8_t __attribute__((ext_vector_type(8)));
typedef float   float4_t __attribute__((ext_vector_type(4)));

static __device__ __forceinline__ half2_t cvt_pk(float a, float b) {
    return __builtin_bit_cast(half2_t, __builtin_amdgcn_cvt_pkrtz(a, b));
}
static __device__ __forceinline__ half4_t cvt_pk4(float a, float b, float c, float d) {
    half2_t lo = cvt_pk(a, b), hi = cvt_pk(c, d);
    half4_t r;
    r[0] = lo[0]; r[1] = lo[1]; r[2] = hi[0]; r[3] = hi[1];
    return r;
}

namespace {
constexpr int kB      = 16;    // batch
constexpr int kL      = 4096;  // Lq == Lk
constexpr int kD      = 64;    // head dim
constexpr int kQTile  = 128;   // 4 waves x 32 q-rows per group
constexpr int kBK     = 64;    // keys per iteration
constexpr int kStride = 72;    // padded LDS row stride (halves)
constexpr int kTileHalfs = kBK * kStride;   // 4608 halves per tile
constexpr int kGrpHalfs  = 2 * kTileHalfs;  // K + V buffers per group
}

// Flash attention fwd v6 = R4 inner loop (register prefetch, 4 waves x 32
// q-rows — proven shape) + IN-BLOCK split-K: 512-thread blocks, 2 wave-groups
// of 4; group g owns keys [g*2048,(g+1)*2048) with its own K/V LDS buffers and
// runs the same 32-iteration loop in lockstep (block barriers align). This
// doubles waves/CU (8 -> 16) with ZERO extra HBM traffic (R5's HBM split-K
// thrashed L2: 822 MB fetch) and UNCHANGED per-wave per-iter work (R3's
// shrink-the-wave doubled LDS traffic). Final LSE merge through LDS, one shot.
__global__ __launch_bounds__(512, 4)
void fa_fwd(const float* __restrict__ Q, const float* __restrict__ K,
            const float* __restrict__ V, const float* __restrict__ scale_ptr,
            float* __restrict__ Out)
{
    __shared__ __align__(16) char smem[2 * kGrpHalfs * sizeof(_Float16)];  // 36,864 B

    const int tid  = threadIdx.x;
    const int wave = tid >> 6;
    const int g    = wave >> 2;   // key-split group (0: keys 0..2047, 1: 2048..4095)
    const int w4   = wave & 3;    // wave within group
    const int tg   = tid & 255;   // thread within group
    const int lane = tid & 63;
    const int c    = lane & 15;   // intra-16 index (q-col in S^T, d-col in O)
    const int qd   = lane >> 4;   // quad 0..3

    _Float16* Ksh = (_Float16*)smem + g * kGrpHalfs;  // Ksh[key][d]
    _Float16* Vsh = Ksh + kTileHalfs;                 // Vsh[d][key] (transposed)

    const int b   = blockIdx.y;
    const int q0  = blockIdx.x * kQTile + w4 * 32;
    const int ks0 = g * (kL / 2);
    const int ks1 = ks0 + kL / 2;

    // fold 1/scale and log2(e) into Q so softmax uses raw exp2
    const float qscale = 1.4426950408889634f / scale_ptr[0];

    const float* Qb = Q + (size_t)b * kL * kD;
    const float* Kb = K + (size_t)b * kL * kD;
    const float* Vb = V + (size_t)b * kL * kD;

    // ---- Q fragments (B-operand of 16x16x32: n=lane&15=qrow, k=8*quad+j=d) ----
    half8_t qfrag[2][2];
#pragma unroll
    for (int qt = 0; qt < 2; ++qt) {
        const float* qrow = Qb + (size_t)(q0 + qt * 16 + c) * kD;
#pragma unroll
        for (int dk = 0; dk < 2; ++dk) {
            const float* p = qrow + dk * 32 + qd * 8;
            half8_t h;
#pragma unroll
            for (int j = 0; j < 8; ++j) h[j] = (_Float16)(p[j] * qscale);
            qfrag[qt][dk] = h;
        }
    }

    float4_t O[2][4];
#pragma unroll
    for (int qt = 0; qt < 2; ++qt)
#pragma unroll
        for (int dt = 0; dt < 4; ++dt) O[qt][dt] = (float4_t)0.0f;

    float m_run[2] = {-__builtin_inff(), -__builtin_inff()};
    float lpart[2] = {0.0f, 0.0f};

    // ---- prefetch this group's first tile into registers ----
    float4 pk[4], pv[4];
#pragma unroll
    for (int i = 0; i < 4; ++i) {
        const int tk = tg + 256 * i;
        pk[i] = *(const float4*)(Kb + (size_t)(ks0 + (tk >> 4)) * kD + (tk & 15) * 4);
        pv[i] = *(const float4*)(Vb + (size_t)(ks0 + (tk & 63)) * kD + (tk >> 6) * 4);
    }

    for (int kb = ks0; kb < ks1; kb += kBK) {
        __syncthreads();  // previous tile's readers done (both groups in lockstep)

        // ---- commit prefetched tile to this group's LDS (fp32 -> fp16) ----
#pragma unroll
        for (int i = 0; i < 4; ++i) {
            const int tk = tg + 256 * i;
            *(half4_t*)(&Ksh[(tk >> 4) * kStride + (tk & 15) * 4]) =
                cvt_pk4(pk[i].x, pk[i].y, pk[i].z, pk[i].w);
        }
#pragma unroll
        for (int i = 0; i < 4; ++i) {
            const int tk  = tg + 256 * i;
            const int row = tk & 63;
            const int c4  = tk >> 6;
            Vsh[(c4 * 4 + 0) * kStride + row] = (_Float16)pv[i].x;
            Vsh[(c4 * 4 + 1) * kStride + row] = (_Float16)pv[i].y;
            Vsh[(c4 * 4 + 2) * kStride + row] = (_Float16)pv[i].z;
            Vsh[(c4 * 4 + 3) * kStride + row] = (_Float16)pv[i].w;
        }
        __syncthreads();

        // ---- prefetch NEXT tile (clamped re-read of first tile on last iter) ----
        {
            const int nb = (kb + kBK < ks1) ? kb + kBK : ks0;
            const float* Kn = Kb + (size_t)nb * kD;
            const float* Vn = Vb + (size_t)nb * kD;
#pragma unroll
            for (int i = 0; i < 4; ++i) {
                const int tk = tg + 256 * i;
                pk[i] = *(const float4*)(Kn + (size_t)(tk >> 4) * kD + (tk & 15) * 4);
                pv[i] = *(const float4*)(Vn + (size_t)(tk & 63) * kD + (tk >> 6) * 4);
            }
        }

        // ---- K fragments (A-operand: m=lane&15=key, k=8*quad+j=d) ----
        half8_t kf[4][2];
#pragma unroll
        for (int kt = 0; kt < 4; ++kt)
#pragma unroll
            for (int dk = 0; dk < 2; ++dk)
                kf[kt][dk] = *(const half8_t*)(&Ksh[(kt * 16 + c) * kStride + dk * 32 + qd * 8]);

        // ---- S^T = K * Q^T  (C-init = -32: free shift, fp16 overflow margin) ----
        float4_t S[4][2];
#pragma unroll
        for (int kt = 0; kt < 4; ++kt)
#pragma unroll
            for (int qt = 0; qt < 2; ++qt) {
                float4_t acc = {-32.0f, -32.0f, -32.0f, -32.0f};
                acc = __builtin_amdgcn_mfma_f32_16x16x32_f16(kf[kt][0], qfrag[qt][0], acc, 0, 0, 0);
                acc = __builtin_amdgcn_mfma_f32_16x16x32_f16(kf[kt][1], qfrag[qt][1], acc, 0, 0, 0);
                S[kt][qt] = acc;
            }

        // ---- online softmax per q-tile (S^T layout: lane column = q-row = c) ----
        half4_t pf[4][2];
#pragma unroll
        for (int qt = 0; qt < 2; ++qt) {
            float tm = S[0][qt][0];
#pragma unroll
            for (int kt = 0; kt < 4; ++kt)
#pragma unroll
                for (int r = 0; r < 4; ++r) tm = fmaxf(tm, S[kt][qt][r]);
            tm = fmaxf(tm, __shfl_xor(tm, 16));
            tm = fmaxf(tm, __shfl_xor(tm, 32));

            const bool newmax = tm > m_run[qt];
            const float mn = newmax ? tm : m_run[qt];
            if (__ballot(newmax)) {  // wave-uniform: skip rescale when no row max moved
                const float alpha = __builtin_amdgcn_exp2f(m_run[qt] - mn);  // 1st iter: 0
                m_run[qt] = mn;
                lpart[qt] *= alpha;
#pragma unroll
                for (int r = 0; r < 4; ++r) {
                    const float a = __shfl(alpha, qd * 4 + r);
#pragma unroll
                    for (int dt = 0; dt < 4; ++dt) O[qt][dt][r] *= a;
                }
            }

            // P = exp2(S - m), per-lane partial l, pack to fp16 A-fragments
#pragma unroll
            for (int kt = 0; kt < 4; ++kt) {
                const float p0 = __builtin_amdgcn_exp2f(S[kt][qt][0] - mn);
                const float p1 = __builtin_amdgcn_exp2f(S[kt][qt][1] - mn);
                const float p2 = __builtin_amdgcn_exp2f(S[kt][qt][2] - mn);
                const float p3 = __builtin_amdgcn_exp2f(S[kt][qt][3] - mn);
                lpart[qt] += (p0 + p1) + (p2 + p3);
                pf[kt][qt] = cvt_pk4(p0, p1, p2, p3);
            }
        }

        // ---- O += P * V  (vf shared across both q-tiles) ----
#pragma unroll
        for (int kt = 0; kt < 4; ++kt)
#pragma unroll
            for (int dt = 0; dt < 4; ++dt) {
                const half4_t vf = *(const half4_t*)(&Vsh[(dt * 16 + c) * kStride + kt * 16 + qd * 4]);
#pragma unroll
                for (int qt = 0; qt < 2; ++qt)
                    O[qt][dt] = __builtin_amdgcn_mfma_f32_16x16x16f16(pf[kt][qt], vf, O[qt][dt], 0, 0, 0);
            }
    }

    // ---- per-row l reduction (both groups) ----
#pragma unroll
    for (int qt = 0; qt < 2; ++qt) {
        lpart[qt] += __shfl_xor(lpart[qt], 16);
        lpart[qt] += __shfl_xor(lpart[qt], 32);
    }

    __syncthreads();  // all tile LDS traffic done; smem reused for the merge

    // combine area (aliases the tile buffers):
    //   Osh: [w4][32 rows][64 d] fp32 = 32 KB;  Msh/Lsh: [w4*2+qt][16] fp32
    float* Osh = (float*)smem;
    float* Msh = Osh + 4 * 32 * 64;
    float* Lsh = Msh + 128;

    if (g == 1) {  // group 1 publishes unnormalized O + (m,l)
#pragma unroll
        for (int qt = 0; qt < 2; ++qt) {
#pragma unroll
            for (int r = 0; r < 4; ++r) {
                const int row = qt * 16 + qd * 4 + r;
                float* op = Osh + w4 * 2048 + row * 64;
#pragma unroll
                for (int dt = 0; dt < 4; ++dt)
                    op[dt * 16 + c] = O[qt][dt][r];
            }
            if (qd == 0) {
                Msh[(w4 * 2 + qt) * 16 + c] = m_run[qt];
                Lsh[(w4 * 2 + qt) * 16 + c] = lpart[qt];
            }
        }
    }
    __syncthreads();

    if (g == 0) {  // group 0 merges (LSE) and writes Out
#pragma unroll
        for (int qt = 0; qt < 2; ++qt)
#pragma unroll
            for (int r = 0; r < 4; ++r) {
                const int row   = qt * 16 + qd * 4 + r;
                const float m0r = __shfl(m_run[qt], qd * 4 + r);
                const float l0r = __shfl(lpart[qt], qd * 4 + r);
                const float m1r = Msh[(w4 * 2 + qt) * 16 + qd * 4 + r];
                const float l1r = Lsh[(w4 * 2 + qt) * 16 + qd * 4 + r];
                const float M   = fmaxf(m0r, m1r);
                const float w0  = __builtin_amdgcn_exp2f(m0r - M);
                const float w1  = __builtin_amdgcn_exp2f(m1r - M);
                const float inv = 1.0f / (l0r * w0 + l1r * w1);
                const float* osrc = Osh + w4 * 2048 + row * 64;
                float* op = Out + ((size_t)b * kL + q0 + row) * kD;
#pragma unroll
                for (int dt = 0; dt < 4; ++dt)
                    op[dt * 16 + c] = (O[qt][dt][r] * w0 + osrc[dt * 16 + c] * w1) * inv;
            }
    }
}

extern "C" void kernel_launch(void* const* d_in, const int* in_sizes, int n_in,
                              void* d_out, int out_size, void* d_ws, size_t ws_size,
                              hipStream_t stream) {
    const float* Q = (const float*)d_in[0];
    const float* K = (const float*)d_in[1];
    const float* V = (const float*)d_in[2];
    const float* s = (const float*)d_in[3];
    float* out = (float*)d_out;
    dim3 grid(kL / kQTile, kB, 1);
    dim3 block(512, 1, 1);
    fa_fwd<<<grid, block, 0, stream>>>(Q, K, V, s, out);
}

// Round 7
// 233.708 us; speedup vs baseline: 2.2699x; 2.2699x over previous
//
#include <hip/hip_runtime.h>
#include <hip/hip_fp16.h>

typedef _Float16 half2_t __attribute__((ext_vector_type(2)));
typedef _Float16 half4_t __attribute__((ext_vector_type(4)));
typedef _Float16 half8_t __attribute__((ext_vector_type(8)));
typedef float   float4_t __attribute__((ext_vector_type(4)));

static __device__ __forceinline__ half2_t cvt_pk(float a, float b) {
    return __builtin_bit_cast(half2_t, __builtin_amdgcn_cvt_pkrtz(a, b));
}
static __device__ __forceinline__ half4_t cvt_pk4(float a, float b, float c, float d) {
    half2_t lo = cvt_pk(a, b), hi = cvt_pk(c, d);
    half4_t r;
    r[0] = lo[0]; r[1] = lo[1]; r[2] = hi[0]; r[3] = hi[1];
    return r;
}

namespace {
constexpr int kB      = 16;    // batch
constexpr int kL      = 4096;  // Lq == Lk
constexpr int kD      = 64;    // head dim
constexpr int kQTile  = 128;   // 4 waves x 32 q-rows per group
constexpr int kBK     = 64;    // keys per iteration
constexpr int kStride = 72;    // padded LDS row stride (halves)
constexpr int kTileHalfs = kBK * kStride;   // 4608 halves per tile
constexpr int kGrpHalfs  = 2 * kTileHalfs;  // K + V buffers per group
}

// Flash attention fwd v7 = R6 (in-block split-K: 512-thread blocks, 2
// wave-groups of 4, group g owns keys [g*2048,(g+1)*2048) with private K/V
// LDS buffers, LSE merge through LDS at the end) with the launch-bounds bug
// fixed: R6's __launch_bounds__(512,4) capped VGPRs at 64 < the ~88 this loop
// needs -> scratch spill (855 MB fetch / 588 MB write, 3.4x slowdown).
// (512,2) caps at 128: no spill, and VGPR~88 still admits 2 blocks/CU
// = 16 waves/CU, double R4's latency coverage at zero extra HBM traffic.
__global__ __launch_bounds__(512, 2)
void fa_fwd(const float* __restrict__ Q, const float* __restrict__ K,
            const float* __restrict__ V, const float* __restrict__ scale_ptr,
            float* __restrict__ Out)
{
    __shared__ __align__(16) char smem[2 * kGrpHalfs * sizeof(_Float16)];  // 36,864 B

    const int tid  = threadIdx.x;
    const int wave = tid >> 6;
    const int g    = wave >> 2;   // key-split group (0: keys 0..2047, 1: 2048..4095)
    const int w4   = wave & 3;    // wave within group
    const int tg   = tid & 255;   // thread within group
    const int lane = tid & 63;
    const int c    = lane & 15;   // intra-16 index (q-col in S^T, d-col in O)
    const int qd   = lane >> 4;   // quad 0..3

    _Float16* Ksh = (_Float16*)smem + g * kGrpHalfs;  // Ksh[key][d]
    _Float16* Vsh = Ksh + kTileHalfs;                 // Vsh[d][key] (transposed)

    const int b   = blockIdx.y;
    const int q0  = blockIdx.x * kQTile + w4 * 32;
    const int ks0 = g * (kL / 2);
    const int ks1 = ks0 + kL / 2;

    // fold 1/scale and log2(e) into Q so softmax uses raw exp2
    const float qscale = 1.4426950408889634f / scale_ptr[0];

    const float* Qb = Q + (size_t)b * kL * kD;
    const float* Kb = K + (size_t)b * kL * kD;
    const float* Vb = V + (size_t)b * kL * kD;

    // ---- Q fragments (B-operand of 16x16x32: n=lane&15=qrow, k=8*quad+j=d) ----
    half8_t qfrag[2][2];
#pragma unroll
    for (int qt = 0; qt < 2; ++qt) {
        const float* qrow = Qb + (size_t)(q0 + qt * 16 + c) * kD;
#pragma unroll
        for (int dk = 0; dk < 2; ++dk) {
            const float* p = qrow + dk * 32 + qd * 8;
            half8_t h;
#pragma unroll
            for (int j = 0; j < 8; ++j) h[j] = (_Float16)(p[j] * qscale);
            qfrag[qt][dk] = h;
        }
    }

    float4_t O[2][4];
#pragma unroll
    for (int qt = 0; qt < 2; ++qt)
#pragma unroll
        for (int dt = 0; dt < 4; ++dt) O[qt][dt] = (float4_t)0.0f;

    float m_run[2] = {-__builtin_inff(), -__builtin_inff()};
    float lpart[2] = {0.0f, 0.0f};

    // ---- prefetch this group's first tile into registers ----
    float4 pk[4], pv[4];
#pragma unroll
    for (int i = 0; i < 4; ++i) {
        const int tk = tg + 256 * i;
        pk[i] = *(const float4*)(Kb + (size_t)(ks0 + (tk >> 4)) * kD + (tk & 15) * 4);
        pv[i] = *(const float4*)(Vb + (size_t)(ks0 + (tk & 63)) * kD + (tk >> 6) * 4);
    }

    for (int kb = ks0; kb < ks1; kb += kBK) {
        __syncthreads();  // previous tile's readers done (both groups in lockstep)

        // ---- commit prefetched tile to this group's LDS (fp32 -> fp16) ----
#pragma unroll
        for (int i = 0; i < 4; ++i) {
            const int tk = tg + 256 * i;
            *(half4_t*)(&Ksh[(tk >> 4) * kStride + (tk & 15) * 4]) =
                cvt_pk4(pk[i].x, pk[i].y, pk[i].z, pk[i].w);
        }
#pragma unroll
        for (int i = 0; i < 4; ++i) {
            const int tk  = tg + 256 * i;
            const int row = tk & 63;
            const int c4  = tk >> 6;
            Vsh[(c4 * 4 + 0) * kStride + row] = (_Float16)pv[i].x;
            Vsh[(c4 * 4 + 1) * kStride + row] = (_Float16)pv[i].y;
            Vsh[(c4 * 4 + 2) * kStride + row] = (_Float16)pv[i].z;
            Vsh[(c4 * 4 + 3) * kStride + row] = (_Float16)pv[i].w;
        }
        __syncthreads();

        // ---- prefetch NEXT tile (clamped re-read of first tile on last iter) ----
        {
            const int nb = (kb + kBK < ks1) ? kb + kBK : ks0;
            const float* Kn = Kb + (size_t)nb * kD;
            const float* Vn = Vb + (size_t)nb * kD;
#pragma unroll
            for (int i = 0; i < 4; ++i) {
                const int tk = tg + 256 * i;
                pk[i] = *(const float4*)(Kn + (size_t)(tk >> 4) * kD + (tk & 15) * 4);
                pv[i] = *(const float4*)(Vn + (size_t)(tk & 63) * kD + (tk >> 6) * 4);
            }
        }

        // ---- K fragments (A-operand: m=lane&15=key, k=8*quad+j=d) ----
        half8_t kf[4][2];
#pragma unroll
        for (int kt = 0; kt < 4; ++kt)
#pragma unroll
            for (int dk = 0; dk < 2; ++dk)
                kf[kt][dk] = *(const half8_t*)(&Ksh[(kt * 16 + c) * kStride + dk * 32 + qd * 8]);

        // ---- S^T = K * Q^T  (C-init = -32: free shift, fp16 overflow margin) ----
        float4_t S[4][2];
#pragma unroll
        for (int kt = 0; kt < 4; ++kt)
#pragma unroll
            for (int qt = 0; qt < 2; ++qt) {
                float4_t acc = {-32.0f, -32.0f, -32.0f, -32.0f};
                acc = __builtin_amdgcn_mfma_f32_16x16x32_f16(kf[kt][0], qfrag[qt][0], acc, 0, 0, 0);
                acc = __builtin_amdgcn_mfma_f32_16x16x32_f16(kf[kt][1], qfrag[qt][1], acc, 0, 0, 0);
                S[kt][qt] = acc;
            }

        // ---- online softmax per q-tile (S^T layout: lane column = q-row = c) ----
        half4_t pf[4][2];
#pragma unroll
        for (int qt = 0; qt < 2; ++qt) {
            float tm = S[0][qt][0];
#pragma unroll
            for (int kt = 0; kt < 4; ++kt)
#pragma unroll
                for (int r = 0; r < 4; ++r) tm = fmaxf(tm, S[kt][qt][r]);
            tm = fmaxf(tm, __shfl_xor(tm, 16));
            tm = fmaxf(tm, __shfl_xor(tm, 32));

            const bool newmax = tm > m_run[qt];
            const float mn = newmax ? tm : m_run[qt];
            if (__ballot(newmax)) {  // wave-uniform: skip rescale when no row max moved
                const float alpha = __builtin_amdgcn_exp2f(m_run[qt] - mn);  // 1st iter: 0
                m_run[qt] = mn;
                lpart[qt] *= alpha;
#pragma unroll
                for (int r = 0; r < 4; ++r) {
                    const float a = __shfl(alpha, qd * 4 + r);
#pragma unroll
                    for (int dt = 0; dt < 4; ++dt) O[qt][dt][r] *= a;
                }
            }

            // P = exp2(S - m), per-lane partial l, pack to fp16 A-fragments
#pragma unroll
            for (int kt = 0; kt < 4; ++kt) {
                const float p0 = __builtin_amdgcn_exp2f(S[kt][qt][0] - mn);
                const float p1 = __builtin_amdgcn_exp2f(S[kt][qt][1] - mn);
                const float p2 = __builtin_amdgcn_exp2f(S[kt][qt][2] - mn);
                const float p3 = __builtin_amdgcn_exp2f(S[kt][qt][3] - mn);
                lpart[qt] += (p0 + p1) + (p2 + p3);
                pf[kt][qt] = cvt_pk4(p0, p1, p2, p3);
            }
        }

        // ---- O += P * V  (vf shared across both q-tiles) ----
#pragma unroll
        for (int kt = 0; kt < 4; ++kt)
#pragma unroll
            for (int dt = 0; dt < 4; ++dt) {
                const half4_t vf = *(const half4_t*)(&Vsh[(dt * 16 + c) * kStride + kt * 16 + qd * 4]);
#pragma unroll
                for (int qt = 0; qt < 2; ++qt)
                    O[qt][dt] = __builtin_amdgcn_mfma_f32_16x16x16f16(pf[kt][qt], vf, O[qt][dt], 0, 0, 0);
            }
    }

    // ---- per-row l reduction (both groups) ----
#pragma unroll
    for (int qt = 0; qt < 2; ++qt) {
        lpart[qt] += __shfl_xor(lpart[qt], 16);
        lpart[qt] += __shfl_xor(lpart[qt], 32);
    }

    __syncthreads();  // all tile LDS traffic done; smem reused for the merge

    // combine area (aliases the tile buffers):
    //   Osh: [w4][32 rows][64 d] fp32 = 32 KB;  Msh/Lsh: [w4*2+qt][16] fp32
    float* Osh = (float*)smem;
    float* Msh = Osh + 4 * 32 * 64;
    float* Lsh = Msh + 128;

    if (g == 1) {  // group 1 publishes unnormalized O + (m,l)
#pragma unroll
        for (int qt = 0; qt < 2; ++qt) {
#pragma unroll
            for (int r = 0; r < 4; ++r) {
                const int row = qt * 16 + qd * 4 + r;
                float* op = Osh + w4 * 2048 + row * 64;
#pragma unroll
                for (int dt = 0; dt < 4; ++dt)
                    op[dt * 16 + c] = O[qt][dt][r];
            }
            if (qd == 0) {
                Msh[(w4 * 2 + qt) * 16 + c] = m_run[qt];
                Lsh[(w4 * 2 + qt) * 16 + c] = lpart[qt];
            }
        }
    }
    __syncthreads();

    if (g == 0) {  // group 0 merges (LSE) and writes Out
#pragma unroll
        for (int qt = 0; qt < 2; ++qt)
#pragma unroll
            for (int r = 0; r < 4; ++r) {
                const int row   = qt * 16 + qd * 4 + r;
                const float m0r = __shfl(m_run[qt], qd * 4 + r);
                const float l0r = __shfl(lpart[qt], qd * 4 + r);
                const float m1r = Msh[(w4 * 2 + qt) * 16 + qd * 4 + r];
                const float l1r = Lsh[(w4 * 2 + qt) * 16 + qd * 4 + r];
                const float M   = fmaxf(m0r, m1r);
                const float w0  = __builtin_amdgcn_exp2f(m0r - M);
                const float w1  = __builtin_amdgcn_exp2f(m1r - M);
                const float inv = 1.0f / (l0r * w0 + l1r * w1);
                const float* osrc = Osh + w4 * 2048 + row * 64;
                float* op = Out + ((size_t)b * kL + q0 + row) * kD;
#pragma unroll
                for (int dt = 0; dt < 4; ++dt)
                    op[dt * 16 + c] = (O[qt][dt][r] * w0 + osrc[dt * 16 + c] * w1) * inv;
            }
    }
}

extern "C" void kernel_launch(void* const* d_in, const int* in_sizes, int n_in,
                              void* d_out, int out_size, void* d_ws, size_t ws_size,
                              hipStream_t stream) {
    const float* Q = (const float*)d_in[0];
    const float* K = (const float*)d_in[1];
    const float* V = (const float*)d_in[2];
    const float* s = (const float*)d_in[3];
    float* out = (float*)d_out;
    dim3 grid(kL / kQTile, kB, 1);
    dim3 block(512, 1, 1);
    fa_fwd<<<grid, block, 0, stream>>>(Q, K, V, s, out);
}

// Round 8
// 204.887 us; speedup vs baseline: 2.5893x; 1.1407x over previous
//
#include <hip/hip_runtime.h>
#include <hip/hip_fp16.h>

typedef _Float16 half2_t __attribute__((ext_vector_type(2)));
typedef _Float16 half4_t __attribute__((ext_vector_type(4)));
typedef _Float16 half8_t __attribute__((ext_vector_type(8)));
typedef float   float4_t __attribute__((ext_vector_type(4)));

static __device__ __forceinline__ half2_t cvt_pk(float a, float b) {
    return __builtin_bit_cast(half2_t, __builtin_amdgcn_cvt_pkrtz(a, b));
}
static __device__ __forceinline__ half4_t cvt_pk4(float a, float b, float c, float d) {
    half2_t lo = cvt_pk(a, b), hi = cvt_pk(c, d);
    half4_t r;
    r[0] = lo[0]; r[1] = lo[1]; r[2] = hi[0]; r[3] = hi[1];
    return r;
}

namespace {
constexpr int kB       = 16;    // batch
constexpr int kL       = 4096;  // Lq == Lk
constexpr int kD       = 64;    // head dim
constexpr int kQTile   = 128;   // 4 waves x 32 q-rows
constexpr int kBK      = 64;    // keys per iteration
constexpr int kKStride = 72;    // Ksh stride (halves): 36 dwords -> kf b128 conflict-free, 16B-aligned
constexpr int kVStride = 68;    // Vsh stride (halves): 34 dwords -> vf b64 conflict-free (b64-only buffer)
}

// Flash attention fwd v8 = R4 (register prefetch, 4 waves x 32 q-rows,
// 2 blocks/CU) with the LDS pipe rebuilt from bank math:
//  - V staged via coalesced scalar reads (lane=d) so the transpose writes are
//    4x ds_write_b64/thread (was 16x ds_write_b16: ~96 issue-cyc/wave-iter).
//  - Vsh stride 68 halves: vf b64 read start-banks 2(c+qd) -> 4 acc/bank =
//    minimum (stride 72 gave 8 -> 2x conflict on all 16 vf reads).
//  - K staged as 2x ds_write_b128/thread (8 consecutive floats/thread),
//    conflict-free; Ksh keeps stride 72 for conflict-free aligned kf b128.
// Occupancy levers (R3/R5/R6/R7) are dead ends at this problem size; this
// attacks the measured ~60 us of serialized per-CU LDS-unit time instead.
__global__ __launch_bounds__(256, 2)
void fa_fwd(const float* __restrict__ Q, const float* __restrict__ K,
            const float* __restrict__ V, const float* __restrict__ scale_ptr,
            float* __restrict__ Out)
{
    __shared__ __align__(16) _Float16 Ksh[kBK * kKStride];  // Ksh[key][d]
    __shared__ __align__(16) _Float16 Vsh[kD * kVStride];   // Vsh[d][key] (transposed)

    const int tid  = threadIdx.x;
    const int wave = tid >> 6;
    const int lane = tid & 63;
    const int c    = lane & 15;   // intra-16 index (q-col in S^T, d-col in O)
    const int qd   = lane >> 4;   // quad 0..3

    const int b  = blockIdx.y;
    const int q0 = blockIdx.x * kQTile + wave * 32;

    // staging decompositions
    const int vd = tid & 63;      // V: this thread's d-column
    const int vk = tid >> 6;      // V: key sub-group (0..3)

    // fold 1/scale and log2(e) into Q so softmax uses raw exp2
    const float qscale = 1.4426950408889634f / scale_ptr[0];

    const float* Qb = Q + (size_t)b * kL * kD;
    const float* Kb = K + (size_t)b * kL * kD;
    const float* Vb = V + (size_t)b * kL * kD;

    // ---- Q fragments (B-operand of 16x16x32: n=lane&15=qrow, k=8*quad+j=d) ----
    half8_t qfrag[2][2];
#pragma unroll
    for (int qt = 0; qt < 2; ++qt) {
        const float* qrow = Qb + (size_t)(q0 + qt * 16 + c) * kD;
#pragma unroll
        for (int dk = 0; dk < 2; ++dk) {
            const float* p = qrow + dk * 32 + qd * 8;
            half8_t h;
#pragma unroll
            for (int j = 0; j < 8; ++j) h[j] = (_Float16)(p[j] * qscale);
            qfrag[qt][dk] = h;
        }
    }

    float4_t O[2][4];
#pragma unroll
    for (int qt = 0; qt < 2; ++qt)
#pragma unroll
        for (int dt = 0; dt < 4; ++dt) O[qt][dt] = (float4_t)0.0f;

    float m_run[2] = {-__builtin_inff(), -__builtin_inff()};
    float lpart[2] = {0.0f, 0.0f};

    // ---- prefetch tile 0 ----
    // K: thread owns 8 consecutive floats of row (tid+256*i2)>>3
    float4 pka[2], pkb[2];
    // V: thread owns d=vd, keys i*16+vk*4+j  (coalesced: lanes span d)
    float pv[16];
#pragma unroll
    for (int i2 = 0; i2 < 2; ++i2) {
        const int tk = tid + 256 * i2;
        const float* src = Kb + (size_t)(tk >> 3) * kD + (tk & 7) * 8;
        pka[i2] = *(const float4*)(src);
        pkb[i2] = *(const float4*)(src + 4);
    }
#pragma unroll
    for (int i = 0; i < 4; ++i)
#pragma unroll
        for (int j = 0; j < 4; ++j)
            pv[i * 4 + j] = Vb[(size_t)(i * 16 + vk * 4 + j) * kD + vd];

    for (int kb = 0; kb < kL; kb += kBK) {
        __syncthreads();  // previous tile's readers done; drains prefetch vmcnt

        // ---- commit K (2x b128, conflict-free) ----
#pragma unroll
        for (int i2 = 0; i2 < 2; ++i2) {
            const int tk = tid + 256 * i2;
            half4_t lo = cvt_pk4(pka[i2].x, pka[i2].y, pka[i2].z, pka[i2].w);
            half4_t hi = cvt_pk4(pkb[i2].x, pkb[i2].y, pkb[i2].z, pkb[i2].w);
            half8_t h8 = __builtin_shufflevector(lo, hi, 0, 1, 2, 3, 4, 5, 6, 7);
            *(half8_t*)(&Ksh[(tk >> 3) * kKStride + (tk & 7) * 8]) = h8;
        }
        // ---- commit V transposed (4x b64, conflict-free) ----
#pragma unroll
        for (int i = 0; i < 4; ++i) {
            *(half4_t*)(&Vsh[vd * kVStride + i * 16 + vk * 4]) =
                cvt_pk4(pv[i * 4 + 0], pv[i * 4 + 1], pv[i * 4 + 2], pv[i * 4 + 3]);
        }
        __syncthreads();

        // ---- prefetch NEXT tile (clamped re-read of tile 0 on last iter) ----
        {
            const int nb = (kb + kBK < kL) ? kb + kBK : 0;
            const float* Kn = Kb + (size_t)nb * kD;
            const float* Vn = Vb + (size_t)nb * kD;
#pragma unroll
            for (int i2 = 0; i2 < 2; ++i2) {
                const int tk = tid + 256 * i2;
                const float* src = Kn + (size_t)(tk >> 3) * kD + (tk & 7) * 8;
                pka[i2] = *(const float4*)(src);
                pkb[i2] = *(const float4*)(src + 4);
            }
#pragma unroll
            for (int i = 0; i < 4; ++i)
#pragma unroll
                for (int j = 0; j < 4; ++j)
                    pv[i * 4 + j] = Vn[(size_t)(i * 16 + vk * 4 + j) * kD + vd];
        }

        // ---- K fragments (A-operand: m=lane&15=key, k=8*quad+j=d) ----
        half8_t kf[4][2];
#pragma unroll
        for (int kt = 0; kt < 4; ++kt)
#pragma unroll
            for (int dk = 0; dk < 2; ++dk)
                kf[kt][dk] = *(const half8_t*)(&Ksh[(kt * 16 + c) * kKStride + dk * 32 + qd * 8]);

        // ---- S^T = K * Q^T  (C-init = -32: free shift, fp16 overflow margin) ----
        float4_t S[4][2];
#pragma unroll
        for (int kt = 0; kt < 4; ++kt)
#pragma unroll
            for (int qt = 0; qt < 2; ++qt) {
                float4_t acc = {-32.0f, -32.0f, -32.0f, -32.0f};
                acc = __builtin_amdgcn_mfma_f32_16x16x32_f16(kf[kt][0], qfrag[qt][0], acc, 0, 0, 0);
                acc = __builtin_amdgcn_mfma_f32_16x16x32_f16(kf[kt][1], qfrag[qt][1], acc, 0, 0, 0);
                S[kt][qt] = acc;
            }

        // ---- online softmax per q-tile (S^T layout: lane column = q-row = c) ----
        half4_t pf[4][2];
#pragma unroll
        for (int qt = 0; qt < 2; ++qt) {
            float tm = S[0][qt][0];
#pragma unroll
            for (int kt = 0; kt < 4; ++kt)
#pragma unroll
                for (int r = 0; r < 4; ++r) tm = fmaxf(tm, S[kt][qt][r]);
            tm = fmaxf(tm, __shfl_xor(tm, 16));
            tm = fmaxf(tm, __shfl_xor(tm, 32));

            const bool newmax = tm > m_run[qt];
            const float mn = newmax ? tm : m_run[qt];
            if (__ballot(newmax)) {  // wave-uniform: skip rescale when no row max moved
                const float alpha = __builtin_amdgcn_exp2f(m_run[qt] - mn);  // 1st iter: 0
                m_run[qt] = mn;
                lpart[qt] *= alpha;
#pragma unroll
                for (int r = 0; r < 4; ++r) {
                    const float a = __shfl(alpha, qd * 4 + r);
#pragma unroll
                    for (int dt = 0; dt < 4; ++dt) O[qt][dt][r] *= a;
                }
            }

            // P = exp2(S - m), per-lane partial l, pack to fp16 A-fragments
#pragma unroll
            for (int kt = 0; kt < 4; ++kt) {
                const float p0 = __builtin_amdgcn_exp2f(S[kt][qt][0] - mn);
                const float p1 = __builtin_amdgcn_exp2f(S[kt][qt][1] - mn);
                const float p2 = __builtin_amdgcn_exp2f(S[kt][qt][2] - mn);
                const float p3 = __builtin_amdgcn_exp2f(S[kt][qt][3] - mn);
                lpart[qt] += (p0 + p1) + (p2 + p3);
                pf[kt][qt] = cvt_pk4(p0, p1, p2, p3);
            }
        }

        // ---- O += P * V  (vf shared across both q-tiles; b64 conflict-free) ----
#pragma unroll
        for (int kt = 0; kt < 4; ++kt)
#pragma unroll
            for (int dt = 0; dt < 4; ++dt) {
                const half4_t vf = *(const half4_t*)(&Vsh[(dt * 16 + c) * kVStride + kt * 16 + qd * 4]);
#pragma unroll
                for (int qt = 0; qt < 2; ++qt)
                    O[qt][dt] = __builtin_amdgcn_mfma_f32_16x16x16f16(pf[kt][qt], vf, O[qt][dt], 0, 0, 0);
            }
    }

    // ---- final l reduction (deferred from the loop) ----
#pragma unroll
    for (int qt = 0; qt < 2; ++qt) {
        lpart[qt] += __shfl_xor(lpart[qt], 16);
        lpart[qt] += __shfl_xor(lpart[qt], 32);
    }

    // ---- epilogue: normalize and store (O row = 4*qd+r, col = dt*16+c) ----
#pragma unroll
    for (int qt = 0; qt < 2; ++qt)
#pragma unroll
        for (int r = 0; r < 4; ++r) {
            const float lr  = __shfl(lpart[qt], qd * 4 + r);
            const float inv = 1.0f / lr;
            const int qrow  = q0 + qt * 16 + qd * 4 + r;
            float* op = Out + ((size_t)b * kL + qrow) * kD;
#pragma unroll
            for (int dt = 0; dt < 4; ++dt)
                op[dt * 16 + c] = O[qt][dt][r] * inv;
        }
}

extern "C" void kernel_launch(void* const* d_in, const int* in_sizes, int n_in,
                              void* d_out, int out_size, void* d_ws, size_t ws_size,
                              hipStream_t stream) {
    const float* Q = (const float*)d_in[0];
    const float* K = (const float*)d_in[1];
    const float* V = (const float*)d_in[2];
    const float* s = (const float*)d_in[3];
    float* out = (float*)d_out;
    dim3 grid(kL / kQTile, kB, 1);
    dim3 block(256, 1, 1);
    fa_fwd<<<grid, block, 0, stream>>>(Q, K, V, s, out);
}

// Round 9
// 201.145 us; speedup vs baseline: 2.6374x; 1.0186x over previous
//
#include <hip/hip_runtime.h>
#include <hip/hip_fp16.h>

typedef _Float16 half2_t __attribute__((ext_vector_type(2)));
typedef _Float16 half4_t __attribute__((ext_vector_type(4)));
typedef _Float16 half8_t __attribute__((ext_vector_type(8)));
typedef float   float4_t __attribute__((ext_vector_type(4)));

static __device__ __forceinline__ half2_t cvt_pk(float a, float b) {
    return __builtin_bit_cast(half2_t, __builtin_amdgcn_cvt_pkrtz(a, b));
}
static __device__ __forceinline__ half4_t cvt_pk4(float a, float b, float c, float d) {
    half2_t lo = cvt_pk(a, b), hi = cvt_pk(c, d);
    half4_t r;
    r[0] = lo[0]; r[1] = lo[1]; r[2] = hi[0]; r[3] = hi[1];
    return r;
}

namespace {
constexpr int kB       = 16;    // batch
constexpr int kL       = 4096;  // Lq == Lk
constexpr int kD       = 64;    // head dim
constexpr int kQTile   = 128;   // 4 waves x 32 q-rows
constexpr int kBK      = 128;   // keys staged per barrier-pair (2 compute halves)
constexpr int kKStride = 72;    // Ksh stride (halves): kf b128 conflict-free, 16B-aligned
constexpr int kVStride = 132;   // Vsh stride (halves): 66 dwords -> vf/write b64 conflict-free
}

// Flash attention fwd v9 = R8 (conflict-free LDS staging, register prefetch,
// 4 waves x 32 q-rows) with BK 64 -> 128: keys staged once per barrier-pair,
// then TWO back-to-back 64-key compute sub-phases with no barrier between.
// Rationale: R8 shows ~30% all-pipe idle with 2 barriers x 64 iters phase-
// locking the block's 4 waves; occupancy levers are exhausted (R3/R5/R6/R7).
// Halving barrier phases (64 -> 32 iters) lets sub-phase 1's kf/S-MFMA overlap
// sub-phase 0's softmax tail across the removed barrier. Registers bounded:
// S/pf/kf process one 64-key half at a time; only staging regs grow (+32).
// LDS 35.3 KB (K 128x72 + V 64x132, both strides keep R8's bank math).
__global__ __launch_bounds__(256, 2)
void fa_fwd(const float* __restrict__ Q, const float* __restrict__ K,
            const float* __restrict__ V, const float* __restrict__ scale_ptr,
            float* __restrict__ Out)
{
    __shared__ __align__(16) _Float16 Ksh[kBK * kKStride];  // Ksh[key][d], 18432 B
    __shared__ __align__(16) _Float16 Vsh[kD * kVStride];   // Vsh[d][key], 16896 B

    const int tid  = threadIdx.x;
    const int wave = tid >> 6;
    const int lane = tid & 63;
    const int c    = lane & 15;   // intra-16 index (q-col in S^T, d-col in O)
    const int qd   = lane >> 4;   // quad 0..3

    const int b  = blockIdx.y;
    const int q0 = blockIdx.x * kQTile + wave * 32;

    // staging decompositions
    const int vd = tid & 63;      // V: this thread's d-column
    const int vk = tid >> 6;      // V: key sub-group (0..3)

    // fold 1/scale and log2(e) into Q so softmax uses raw exp2
    const float qscale = 1.4426950408889634f / scale_ptr[0];

    const float* Qb = Q + (size_t)b * kL * kD;
    const float* Kb = K + (size_t)b * kL * kD;
    const float* Vb = V + (size_t)b * kL * kD;

    // ---- Q fragments (B-operand of 16x16x32: n=lane&15=qrow, k=8*quad+j=d) ----
    half8_t qfrag[2][2];
#pragma unroll
    for (int qt = 0; qt < 2; ++qt) {
        const float* qrow = Qb + (size_t)(q0 + qt * 16 + c) * kD;
#pragma unroll
        for (int dk = 0; dk < 2; ++dk) {
            const float* p = qrow + dk * 32 + qd * 8;
            half8_t h;
#pragma unroll
            for (int j = 0; j < 8; ++j) h[j] = (_Float16)(p[j] * qscale);
            qfrag[qt][dk] = h;
        }
    }

    float4_t O[2][4];
#pragma unroll
    for (int qt = 0; qt < 2; ++qt)
#pragma unroll
        for (int dt = 0; dt < 4; ++dt) O[qt][dt] = (float4_t)0.0f;

    float m_run[2] = {-__builtin_inff(), -__builtin_inff()};
    float lpart[2] = {0.0f, 0.0f};

    // ---- prefetch tile 0 (128 keys) ----
    // K: thread owns 8 consecutive floats of row (tid+256*i)>>3, i=0..3
    float4 pka[4], pkb[4];
    // V: thread owns d=vd, keys i*16+vk*4+j, i=0..7 (coalesced: lanes span d)
    float pv[32];
#pragma unroll
    for (int i = 0; i < 4; ++i) {
        const int tk = tid + 256 * i;
        const float* src = Kb + (size_t)(tk >> 3) * kD + (tk & 7) * 8;
        pka[i] = *(const float4*)(src);
        pkb[i] = *(const float4*)(src + 4);
    }
#pragma unroll
    for (int i = 0; i < 8; ++i)
#pragma unroll
        for (int j = 0; j < 4; ++j)
            pv[i * 4 + j] = Vb[(size_t)(i * 16 + vk * 4 + j) * kD + vd];

    for (int kb = 0; kb < kL; kb += kBK) {
        __syncthreads();  // previous tile's readers done; drains prefetch vmcnt

        // ---- commit K (4x b128, conflict-free) ----
#pragma unroll
        for (int i = 0; i < 4; ++i) {
            const int tk = tid + 256 * i;
            half4_t lo = cvt_pk4(pka[i].x, pka[i].y, pka[i].z, pka[i].w);
            half4_t hi = cvt_pk4(pkb[i].x, pkb[i].y, pkb[i].z, pkb[i].w);
            half8_t h8 = __builtin_shufflevector(lo, hi, 0, 1, 2, 3, 4, 5, 6, 7);
            *(half8_t*)(&Ksh[(tk >> 3) * kKStride + (tk & 7) * 8]) = h8;
        }
        // ---- commit V transposed (8x b64, conflict-free) ----
#pragma unroll
        for (int i = 0; i < 8; ++i) {
            *(half4_t*)(&Vsh[vd * kVStride + i * 16 + vk * 4]) =
                cvt_pk4(pv[i * 4 + 0], pv[i * 4 + 1], pv[i * 4 + 2], pv[i * 4 + 3]);
        }
        __syncthreads();

        // ---- prefetch NEXT tile (clamped re-read of tile 0 on last iter) ----
        {
            const int nb = (kb + kBK < kL) ? kb + kBK : 0;
            const float* Kn = Kb + (size_t)nb * kD;
            const float* Vn = Vb + (size_t)nb * kD;
#pragma unroll
            for (int i = 0; i < 4; ++i) {
                const int tk = tid + 256 * i;
                const float* src = Kn + (size_t)(tk >> 3) * kD + (tk & 7) * 8;
                pka[i] = *(const float4*)(src);
                pkb[i] = *(const float4*)(src + 4);
            }
#pragma unroll
            for (int i = 0; i < 8; ++i)
#pragma unroll
                for (int j = 0; j < 4; ++j)
                    pv[i * 4 + j] = Vn[(size_t)(i * 16 + vk * 4 + j) * kD + vd];
        }

        // ---- two 64-key compute halves, no barrier between ----
#pragma unroll
        for (int h = 0; h < 2; ++h) {
            const int kbase = h * 64;

            // K fragments (A-operand: m=lane&15=key, k=8*quad+j=d)
            half8_t kf[4][2];
#pragma unroll
            for (int kt = 0; kt < 4; ++kt)
#pragma unroll
                for (int dk = 0; dk < 2; ++dk)
                    kf[kt][dk] = *(const half8_t*)(
                        &Ksh[(kbase + kt * 16 + c) * kKStride + dk * 32 + qd * 8]);

            // S^T = K * Q^T  (C-init = -32: free shift, fp16 overflow margin)
            float4_t S[4][2];
#pragma unroll
            for (int kt = 0; kt < 4; ++kt)
#pragma unroll
                for (int qt = 0; qt < 2; ++qt) {
                    float4_t acc = {-32.0f, -32.0f, -32.0f, -32.0f};
                    acc = __builtin_amdgcn_mfma_f32_16x16x32_f16(kf[kt][0], qfrag[qt][0], acc, 0, 0, 0);
                    acc = __builtin_amdgcn_mfma_f32_16x16x32_f16(kf[kt][1], qfrag[qt][1], acc, 0, 0, 0);
                    S[kt][qt] = acc;
                }

            // online softmax per q-tile (S^T layout: lane column = q-row = c)
            half4_t pf[4][2];
#pragma unroll
            for (int qt = 0; qt < 2; ++qt) {
                float tm = S[0][qt][0];
#pragma unroll
                for (int kt = 0; kt < 4; ++kt)
#pragma unroll
                    for (int r = 0; r < 4; ++r) tm = fmaxf(tm, S[kt][qt][r]);
                tm = fmaxf(tm, __shfl_xor(tm, 16));
                tm = fmaxf(tm, __shfl_xor(tm, 32));

                const bool newmax = tm > m_run[qt];
                const float mn = newmax ? tm : m_run[qt];
                if (__ballot(newmax)) {  // wave-uniform: skip when no row max moved
                    const float alpha = __builtin_amdgcn_exp2f(m_run[qt] - mn);
                    m_run[qt] = mn;
                    lpart[qt] *= alpha;
#pragma unroll
                    for (int r = 0; r < 4; ++r) {
                        const float a = __shfl(alpha, qd * 4 + r);
#pragma unroll
                        for (int dt = 0; dt < 4; ++dt) O[qt][dt][r] *= a;
                    }
                }

                // P = exp2(S - m), per-lane partial l, pack to fp16 A-fragments
#pragma unroll
                for (int kt = 0; kt < 4; ++kt) {
                    const float p0 = __builtin_amdgcn_exp2f(S[kt][qt][0] - mn);
                    const float p1 = __builtin_amdgcn_exp2f(S[kt][qt][1] - mn);
                    const float p2 = __builtin_amdgcn_exp2f(S[kt][qt][2] - mn);
                    const float p3 = __builtin_amdgcn_exp2f(S[kt][qt][3] - mn);
                    lpart[qt] += (p0 + p1) + (p2 + p3);
                    pf[kt][qt] = cvt_pk4(p0, p1, p2, p3);
                }
            }

            // O += P * V  (vf shared across both q-tiles; b64 conflict-free)
#pragma unroll
            for (int kt = 0; kt < 4; ++kt)
#pragma unroll
                for (int dt = 0; dt < 4; ++dt) {
                    const half4_t vf = *(const half4_t*)(
                        &Vsh[(dt * 16 + c) * kVStride + kbase + kt * 16 + qd * 4]);
#pragma unroll
                    for (int qt = 0; qt < 2; ++qt)
                        O[qt][dt] = __builtin_amdgcn_mfma_f32_16x16x16f16(pf[kt][qt], vf, O[qt][dt], 0, 0, 0);
                }
        }
    }

    // ---- final l reduction (deferred from the loop) ----
#pragma unroll
    for (int qt = 0; qt < 2; ++qt) {
        lpart[qt] += __shfl_xor(lpart[qt], 16);
        lpart[qt] += __shfl_xor(lpart[qt], 32);
    }

    // ---- epilogue: normalize and store (O row = 4*qd+r, col = dt*16+c) ----
#pragma unroll
    for (int qt = 0; qt < 2; ++qt)
#pragma unroll
        for (int r = 0; r < 4; ++r) {
            const float lr  = __shfl(lpart[qt], qd * 4 + r);
            const float inv = 1.0f / lr;
            const int qrow  = q0 + qt * 16 + qd * 4 + r;
            float* op = Out + ((size_t)b * kL + qrow) * kD;
#pragma unroll
            for (int dt = 0; dt < 4; ++dt)
                op[dt * 16 + c] = O[qt][dt][r] * inv;
        }
}

extern "C" void kernel_launch(void* const* d_in, const int* in_sizes, int n_in,
                              void* d_out, int out_size, void* d_ws, size_t ws_size,
                              hipStream_t stream) {
    const float* Q = (const float*)d_in[0];
    const float* K = (const float*)d_in[1];
    const float* V = (const float*)d_in[2];
    const float* s = (const float*)d_in[3];
    float* out = (float*)d_out;
    dim3 grid(kL / kQTile, kB, 1);
    dim3 block(256, 1, 1);
    fa_fwd<<<grid, block, 0, stream>>>(Q, K, V, s, out);
}

// Round 11
// 200.424 us; speedup vs baseline: 2.6469x; 1.0036x over previous
//
#include <hip/hip_runtime.h>
#include <hip/hip_fp16.h>

typedef _Float16 half2_t __attribute__((ext_vector_type(2)));
typedef _Float16 half4_t __attribute__((ext_vector_type(4)));
typedef _Float16 half8_t __attribute__((ext_vector_type(8)));
typedef float   float4_t __attribute__((ext_vector_type(4)));

static __device__ __forceinline__ half2_t cvt_pk(float a, float b) {
    return __builtin_bit_cast(half2_t, __builtin_amdgcn_cvt_pkrtz(a, b));
}
static __device__ __forceinline__ half4_t cvt_pk4(float a, float b, float c, float d) {
    half2_t lo = cvt_pk(a, b), hi = cvt_pk(c, d);
    half4_t r;
    r[0] = lo[0]; r[1] = lo[1]; r[2] = hi[0]; r[3] = hi[1];
    return r;
}
static __device__ __forceinline__ half8_t cvt_pk8(const float4& a, const float4& b) {
    half4_t lo = cvt_pk4(a.x, a.y, a.z, a.w);
    half4_t hi = cvt_pk4(b.x, b.y, b.z, b.w);
    return __builtin_shufflevector(lo, hi, 0, 1, 2, 3, 4, 5, 6, 7);
}

namespace {
constexpr int kB       = 16;    // batch
constexpr int kL       = 4096;  // Lq == Lk
constexpr int kD       = 64;    // head dim
constexpr int kQTile   = 128;   // 4 waves x 32 q-rows
constexpr int kBK      = 64;    // keys per tile
constexpr int kTiles   = kL / kBK;          // 64 key-tiles per batch
constexpr int kTileH   = kBK * kD;          // 4096 halves per tile image
constexpr int kKStride = 72;    // Ksh stride (halves): kf b128 conflict-free, 16B-aligned
constexpr int kVStride = 68;    // Vsh stride (halves): vf b64 conflict-free (b64-only buffer)
constexpr size_t kWsHalves = (size_t)kB * kTiles * kTileH;  // 8 MB per operand
}

// v11: R9's VALU-staging diagnosis, WITHOUT R10's unverifiable DMA primitive.
// Pre-pass converts K -> fp16 tile images (row-major, order = main-loop thread
// consumption) and V -> per-tile V^T fp16 images laid out [chunk][d][8 keys]
// so the main kernel's loads are coalesced 16B/lane. Main-loop staging per
// thread: 4x half8 global loads + 2x ds_write_b128 (K) + 4x ds_write_b64 (V)
// (~22 instrs, was ~150: fp32 loads + pkrtz + transpose arith now off-loop).
// Everything else is byte-identical to proven R8/R9: LDS strides 72/68,
// kf/vf read patterns, two-barrier loop, register prefetch (16 VGPRs, was 48).
// l computed via ones-column MFMA (B=1): lands in O-row layout, removes lpart
// adds + all epilogue shuffles (verified against R9 fragment layouts).

__global__ __launch_bounds__(256) void prep_kv(const float* __restrict__ K,
                                               const float* __restrict__ V,
                                               _Float16* __restrict__ Kws,
                                               _Float16* __restrict__ Vws)
{
    int blk = blockIdx.x;
    const int tid = threadIdx.x;
    if (blk < kB * kTiles) {
        // K image: plain fp16 row-major per tile (half-index task*8, task=r*8+g)
        const float* src = K + (size_t)blk * kTileH;
        _Float16* dst = Kws + (size_t)blk * kTileH;
#pragma unroll
        for (int i = 0; i < 2; ++i) {
            const int task = tid + 256 * i;
            const float* p = src + task * 8;
            const float4 a  = *(const float4*)p;
            const float4 b2 = *(const float4*)(p + 4);
            *(half8_t*)(dst + task * 8) = cvt_pk8(a, b2);
        }
    } else {
        // V^T image: [c8 chunk][d][8 keys] halves; reads coalesced across d
        blk -= kB * kTiles;
        const float* src = V + (size_t)blk * kTileH;   // [key][d]
        _Float16* dst = Vws + (size_t)blk * kTileH;
        const int d  = tid & 63;
        const int vw = tid >> 6;
#pragma unroll
        for (int i = 0; i < 2; ++i) {
            const int c8 = vw * 2 + i;
            const int k0 = c8 * 8;
            float p[8];
#pragma unroll
            for (int j = 0; j < 8; ++j) p[j] = src[(k0 + j) * kD + d];
            half4_t lo = cvt_pk4(p[0], p[1], p[2], p[3]);
            half4_t hi = cvt_pk4(p[4], p[5], p[6], p[7]);
            *(half8_t*)(dst + (c8 * 64 + d) * 8) =
                __builtin_shufflevector(lo, hi, 0, 1, 2, 3, 4, 5, 6, 7);
        }
    }
}

__global__ __launch_bounds__(256, 2)
void fa_fwd(const float* __restrict__ Q, const _Float16* __restrict__ Kws,
            const _Float16* __restrict__ Vws, const float* __restrict__ scale_ptr,
            float* __restrict__ Out)
{
    __shared__ __align__(16) _Float16 Ksh[kBK * kKStride];  // Ksh[key][d]
    __shared__ __align__(16) _Float16 Vsh[kD * kVStride];   // Vsh[d][key] (transposed)

    const int tid  = threadIdx.x;
    const int wave = tid >> 6;
    const int lane = tid & 63;
    const int c    = lane & 15;   // intra-16 index (q-col in S^T, d-col in O)
    const int qd   = lane >> 4;   // quad 0..3

    const int b  = blockIdx.y;
    const int q0 = blockIdx.x * kQTile + wave * 32;

    // staging decompositions (match image layouts)
    const int task0 = tid, task1 = tid + 256;          // K: r=task>>3, g=task&7
    const int vd = tid & 63;                           // V: this thread's d
    const int vw = tid >> 6;                           // V: chunk pair base

    const float qscale = 1.4426950408889634f / scale_ptr[0];

    const float*    Qb = Q   + (size_t)b * kL * kD;
    const _Float16* Kt = Kws + (size_t)b * kTiles * kTileH;
    const _Float16* Vt = Vws + (size_t)b * kTiles * kTileH;

    // ---- Q fragments (B-operand of 16x16x32: n=lane&15=qrow, k=8*quad+j=d) ----
    half8_t qfrag[2][2];
#pragma unroll
    for (int qt = 0; qt < 2; ++qt) {
        const float* qrow = Qb + (size_t)(q0 + qt * 16 + c) * kD;
#pragma unroll
        for (int dk = 0; dk < 2; ++dk) {
            const float* p = qrow + dk * 32 + qd * 8;
            half8_t h;
#pragma unroll
            for (int j = 0; j < 8; ++j) h[j] = (_Float16)(p[j] * qscale);
            qfrag[qt][dk] = h;
        }
    }

    float4_t O[2][4];
    float4_t O5[2];   // l accumulator via ones-column MFMA (O-row layout)
#pragma unroll
    for (int qt = 0; qt < 2; ++qt) {
        O5[qt] = (float4_t)0.0f;
#pragma unroll
        for (int dt = 0; dt < 4; ++dt) O[qt][dt] = (float4_t)0.0f;
    }
    float m_run[2] = {-__builtin_inff(), -__builtin_inff()};

    const half4_t vone = {(_Float16)1.0f, (_Float16)1.0f, (_Float16)1.0f, (_Float16)1.0f};

    // ---- prefetch tile 0 (4x half8 = 16 VGPRs) ----
    half8_t kp[2], vp[2];
    kp[0] = *(const half8_t*)(Kt + task0 * 8);
    kp[1] = *(const half8_t*)(Kt + task1 * 8);
    vp[0] = *(const half8_t*)(Vt + ((vw * 2 + 0) * 64 + vd) * 8);
    vp[1] = *(const half8_t*)(Vt + ((vw * 2 + 1) * 64 + vd) * 8);

    for (int t = 0; t < kTiles; ++t) {
        __syncthreads();  // previous tile's LDS readers done

        // ---- commit K (2x b128) ----
        *(half8_t*)(&Ksh[(task0 >> 3) * kKStride + (task0 & 7) * 8]) = kp[0];
        *(half8_t*)(&Ksh[(task1 >> 3) * kKStride + (task1 & 7) * 8]) = kp[1];
        // ---- commit V (4x b64; Vsh stride 68 is only 8B-aligned) ----
#pragma unroll
        for (int i = 0; i < 2; ++i) {
            const int c8 = vw * 2 + i;
            *(half4_t*)(&Vsh[vd * kVStride + c8 * 8])     =
                __builtin_shufflevector(vp[i], vp[i], 0, 1, 2, 3);
            *(half4_t*)(&Vsh[vd * kVStride + c8 * 8 + 4]) =
                __builtin_shufflevector(vp[i], vp[i], 4, 5, 6, 7);
        }
        __syncthreads();

        // ---- prefetch NEXT tile (wraps to tile 0 on last iter, unused) ----
        {
            const int nt = (t + 1) & (kTiles - 1);
            const _Float16* kn = Kt + (size_t)nt * kTileH;
            const _Float16* vn = Vt + (size_t)nt * kTileH;
            kp[0] = *(const half8_t*)(kn + task0 * 8);
            kp[1] = *(const half8_t*)(kn + task1 * 8);
            vp[0] = *(const half8_t*)(vn + ((vw * 2 + 0) * 64 + vd) * 8);
            vp[1] = *(const half8_t*)(vn + ((vw * 2 + 1) * 64 + vd) * 8);
        }

        // ---- K fragments (A-operand: m=lane&15=key, k=8*quad+j=d) ----
        half8_t kf[4][2];
#pragma unroll
        for (int kt = 0; kt < 4; ++kt)
#pragma unroll
            for (int dk = 0; dk < 2; ++dk)
                kf[kt][dk] = *(const half8_t*)(&Ksh[(kt * 16 + c) * kKStride + dk * 32 + qd * 8]);

        // ---- S^T = K * Q^T  (C-init = -32: free shift, fp16 overflow margin) ----
        float4_t S[4][2];
#pragma unroll
        for (int kt = 0; kt < 4; ++kt)
#pragma unroll
            for (int qt = 0; qt < 2; ++qt) {
                float4_t acc = {-32.0f, -32.0f, -32.0f, -32.0f};
                acc = __builtin_amdgcn_mfma_f32_16x16x32_f16(kf[kt][0], qfrag[qt][0], acc, 0, 0, 0);
                acc = __builtin_amdgcn_mfma_f32_16x16x32_f16(kf[kt][1], qfrag[qt][1], acc, 0, 0, 0);
                S[kt][qt] = acc;
            }

        // ---- online softmax per q-tile (S^T layout: lane column = q-row = c) ----
        half4_t pf[4][2];
#pragma unroll
        for (int qt = 0; qt < 2; ++qt) {
            float tm = S[0][qt][0];
#pragma unroll
            for (int kt = 0; kt < 4; ++kt)
#pragma unroll
                for (int r = 0; r < 4; ++r) tm = fmaxf(tm, S[kt][qt][r]);
            tm = fmaxf(tm, __shfl_xor(tm, 16));
            tm = fmaxf(tm, __shfl_xor(tm, 32));

            const bool newmax = tm > m_run[qt];
            const float mn = newmax ? tm : m_run[qt];
            if (__ballot(newmax)) {  // wave-uniform: skip when no row max moved
                const float alpha = __builtin_amdgcn_exp2f(m_run[qt] - mn);  // 1st iter: 0
                m_run[qt] = mn;
#pragma unroll
                for (int r = 0; r < 4; ++r) {
                    const float a = __shfl(alpha, qd * 4 + r);
#pragma unroll
                    for (int dt = 0; dt < 4; ++dt) O[qt][dt][r] *= a;
                    O5[qt][r] *= a;
                }
            }

            // P = exp2(S - m), pack to fp16 A-fragments (l comes from ones-MFMA)
#pragma unroll
            for (int kt = 0; kt < 4; ++kt) {
                const float p0 = __builtin_amdgcn_exp2f(S[kt][qt][0] - mn);
                const float p1 = __builtin_amdgcn_exp2f(S[kt][qt][1] - mn);
                const float p2 = __builtin_amdgcn_exp2f(S[kt][qt][2] - mn);
                const float p3 = __builtin_amdgcn_exp2f(S[kt][qt][3] - mn);
                pf[kt][qt] = cvt_pk4(p0, p1, p2, p3);
            }
        }

        // ---- O += P*V ; l += P*1  (vf b64 conflict-free, shared across q-tiles) ----
#pragma unroll
        for (int kt = 0; kt < 4; ++kt) {
#pragma unroll
            for (int dt = 0; dt < 4; ++dt) {
                const half4_t vf = *(const half4_t*)(
                    &Vsh[(dt * 16 + c) * kVStride + kt * 16 + qd * 4]);
#pragma unroll
                for (int qt = 0; qt < 2; ++qt)
                    O[qt][dt] = __builtin_amdgcn_mfma_f32_16x16x16f16(pf[kt][qt], vf, O[qt][dt], 0, 0, 0);
            }
#pragma unroll
            for (int qt = 0; qt < 2; ++qt)
                O5[qt] = __builtin_amdgcn_mfma_f32_16x16x16f16(pf[kt][qt], vone, O5[qt], 0, 0, 0);
        }
    }

    // ---- epilogue: l already in O-row layout (no shuffles) ----
#pragma unroll
    for (int qt = 0; qt < 2; ++qt)
#pragma unroll
        for (int r = 0; r < 4; ++r) {
            const float inv = 1.0f / O5[qt][r];
            const int qrow  = q0 + qt * 16 + qd * 4 + r;
            float* op = Out + ((size_t)b * kL + qrow) * kD;
#pragma unroll
            for (int dt = 0; dt < 4; ++dt)
                op[dt * 16 + c] = O[qt][dt][r] * inv;
        }
}

extern "C" void kernel_launch(void* const* d_in, const int* in_sizes, int n_in,
                              void* d_out, int out_size, void* d_ws, size_t ws_size,
                              hipStream_t stream) {
    const float* Q = (const float*)d_in[0];
    const float* K = (const float*)d_in[1];
    const float* V = (const float*)d_in[2];
    const float* s = (const float*)d_in[3];
    float* out = (float*)d_out;
    _Float16* Kws = (_Float16*)d_ws;
    _Float16* Vws = Kws + kWsHalves;   // 16 MB total; ws_size >= 34 MB proven in R5

    prep_kv<<<dim3(2 * kB * kTiles), dim3(256), 0, stream>>>(K, V, Kws, Vws);
    fa_fwd<<<dim3(kL / kQTile, kB, 1), dim3(256), 0, stream>>>(Q, Kws, Vws, s, out);
}